// Round 6
// baseline (265.217 us; speedup 1.0000x reference)
//
#include <hip/hip_runtime.h>
#include <hip/hip_fp16.h>
#include <type_traits>

// Buckets: 512 nodes each, up to 256 buckets (nn <= 131072).
#define NBK 256
#define BSHIFT 9
#define NPB 512

template <int N> struct alignas(4 * N) HVec { __half2 v[N]; };

typedef _Float16 half8 __attribute__((ext_vector_type(8)));
typedef float f32x4 __attribute__((ext_vector_type(4)));

// ---- A1: per-bucket edge histogram ----
__global__ __launch_bounds__(256) void histA_k(const int* __restrict__ dst, int ne,
                                               int* __restrict__ gcount) {
    __shared__ int h[NBK];
    for (int i = threadIdx.x; i < NBK; i += 256) h[i] = 0;
    __syncthreads();
    int e0 = blockIdx.x * 4096;
    int e1 = min(e0 + 4096, ne);
    for (int e = e0 + (int)threadIdx.x; e < e1; e += 256)
        atomicAdd(&h[dst[e] >> BSHIFT], 1);
    __syncthreads();
    for (int i = threadIdx.x; i < NBK; i += 256)
        if (h[i]) atomicAdd(&gcount[i], h[i]);
}

// ---- A2: exclusive scan of bucket counts -> bases + cursors; sentinel rowptr[nn] ----
__global__ __launch_bounds__(256) void scanB_k(const int* __restrict__ gcount,
                                               int* __restrict__ gbase,
                                               int* __restrict__ cursor,
                                               int* __restrict__ rowptr,
                                               int nn, int ne) {
    __shared__ int sh[NBK];
    int t = threadIdx.x;
    int v = gcount[t];
    sh[t] = v;
    __syncthreads();
    for (int d = 1; d < NBK; d <<= 1) {
        int u = (t >= d) ? sh[t - d] : 0;
        __syncthreads();
        sh[t] += u;
        __syncthreads();
    }
    int ex = sh[t] - v;
    gbase[t] = ex;
    cursor[t] = ex;
    if (t == NBK - 1) gbase[NBK] = sh[t];   // == ne
    if (t == 0) rowptr[nn] = ne;
}

// ---- A3: partition edges into bucket regions, packed (dst_local<<17)|src ----
__global__ __launch_bounds__(512) void partA_k(const int* __restrict__ src,
                                               const int* __restrict__ dst,
                                               int* __restrict__ cursor,
                                               int* __restrict__ bucketed, int ne) {
    constexpr int EPB = 8192;
    __shared__ int hist[NBK], lofs[NBK + 1], lcur[NBK], gbs[NBK], sc[NBK];
    __shared__ int stage[EPB];
    int t = threadIdx.x;
    int e0 = blockIdx.x * EPB;
    int e1 = min(e0 + EPB, ne);
    int cnt = e1 - e0;
    for (int i = t; i < NBK; i += 512) hist[i] = 0;
    __syncthreads();
    int sv[16], dv[16];
#pragma unroll
    for (int k = 0; k < 16; k++) {
        int e = e0 + t + k * 512;
        int s = 0, d = 0;
        if (e < e1) {
            s = src[e];
            d = dst[e];
            atomicAdd(&hist[d >> BSHIFT], 1);
        }
        sv[k] = s;
        dv[k] = d;
    }
    __syncthreads();
    if (t < NBK) sc[t] = hist[t];
    __syncthreads();
    for (int d = 1; d < NBK; d <<= 1) {
        int u = 0;
        if (t < NBK && t >= d) u = sc[t - d];
        __syncthreads();
        if (t < NBK) sc[t] += u;
        __syncthreads();
    }
    if (t < NBK) {
        int ex = sc[t] - hist[t];
        lofs[t] = ex;
        lcur[t] = ex;
        gbs[t] = hist[t] ? atomicAdd(&cursor[t], hist[t]) : 0;
    }
    if (t == 0) lofs[NBK] = cnt;
    __syncthreads();
#pragma unroll
    for (int k = 0; k < 16; k++) {
        int e = e0 + t + k * 512;
        if (e < e1) {
            int b = dv[k] >> BSHIFT;
            int q = atomicAdd(&lcur[b], 1);
            stage[q] = ((dv[k] & (NPB - 1)) << 17) | sv[k];
        }
    }
    __syncthreads();
    for (int idx = t; idx < cnt; idx += 512) {
        int lo = 0, hi = NBK;
        while (hi - lo > 1) {
            int mid = (lo + hi) >> 1;
            if (lofs[mid] <= idx) lo = mid; else hi = mid;
        }
        bucketed[gbs[lo] + (idx - lofs[lo])] = stage[idx];
    }
}

// ---- B: per-bucket CSR finalize + rowptr + dinv, all coalesced ----
__global__ __launch_bounds__(1024) void csrB_k(const int* __restrict__ bucketed,
                                               const int* __restrict__ gbase,
                                               int* __restrict__ csr,
                                               int* __restrict__ rowptr,
                                               float* __restrict__ dinv, int nn) {
    constexpr int CAP = 10240;
    __shared__ int cnt[NPB], ofs[NPB], cur[NPB];
    __shared__ int stage[CAP];
    int t = threadIdx.x;
    int b = blockIdx.x;
    int beg = gbase[b], end = gbase[b + 1];
    int m = end - beg;
    if (t < NPB) cnt[t] = 0;
    __syncthreads();
    for (int i = t; i < m; i += 1024)
        atomicAdd(&cnt[bucketed[beg + i] >> 17], 1);
    __syncthreads();
    int v = (t < NPB) ? cnt[t] : 0;
    if (t < NPB) ofs[t] = v;
    __syncthreads();
    for (int d = 1; d < NPB; d <<= 1) {
        int u = 0;
        if (t < NPB && t >= d) u = ofs[t - d];
        __syncthreads();
        if (t < NPB) ofs[t] += u;
        __syncthreads();
    }
    if (t < NPB) {
        int ex = ofs[t] - v;
        cur[t] = ex;
        int node = b * NPB + t;
        if (node < nn) {
            rowptr[node] = beg + ex;
            dinv[node] = rsqrtf((float)(v + 1));   // +1 self-loop
        }
    }
    __syncthreads();
    if (m <= CAP) {
        for (int i = t; i < m; i += 1024) {
            int pv = bucketed[beg + i];
            int p = atomicAdd(&cur[pv >> 17], 1);
            stage[p] = pv & 0x1FFFF;
        }
        __syncthreads();
        for (int i = t; i < m; i += 1024) csr[beg + i] = stage[i];
    } else {
        for (int i = t; i < m; i += 1024) {
            int pv = bucketed[beg + i];
            int p = atomicAdd(&cur[pv >> 17], 1);
            csr[beg + p] = pv & 0x1FFFF;
        }
    }
}

// ---- W prep: transpose + fp16 cast. WT1[j][k] (128x128), WT2[j][k] (64x128) ----
__global__ void prepW_k(const float* __restrict__ W1, const float* __restrict__ W2,
                        _Float16* __restrict__ WT1, _Float16* __restrict__ WT2) {
    int i = blockIdx.x * blockDim.x + threadIdx.x;
    if (i < 128 * 128) {
        int k = i >> 7, j = i & 127;
        WT1[j * 128 + k] = (_Float16)W1[i];
    }
    int i2 = i - 128 * 128;
    if (i2 >= 0 && i2 < 128 * 64) {
        int k = i2 >> 6, j = i2 & 63;
        WT2[j * 128 + k] = (_Float16)W2[i2];
    }
}

// ---------------- MFMA dense transform: H = X @ W, CHUNKED output ----------------
// One wave per 16-row tile. Output layout: H[c][node][16] fp16 (chunk-major),
// chunk stride cs = nn*16. SCALE multiplies rows by dinv (h' = dinv .* XW).
template <int NO, bool SCALE, typename XT>
__global__ __launch_bounds__(256) void gemm_mfma_k(const XT* __restrict__ X,
                                                   const _Float16* __restrict__ WT,
                                                   const float* __restrict__ dinv,
                                                   _Float16* __restrict__ H, int nrows) {
    constexpr int K = 128;
    constexpr int NCT = NO / 16;
    int wv = (int)((blockIdx.x * (size_t)blockDim.x + threadIdx.x) >> 6);
    int r0 = wv * 16;
    if (r0 >= nrows) return;
    int lane = threadIdx.x & 63;
    int lr = lane & 15;          // A-row / D-col
    int kg = lane >> 4;          // k-group
    int rg = r0 + lr;
    if (rg >= nrows) rg = nrows - 1;   // clamp (stores are guarded)
    size_t cs = (size_t)nrows * 16;    // chunk stride

    half8 a[4];
    if constexpr (std::is_same<XT, float>::value) {
#pragma unroll
        for (int ks = 0; ks < 4; ks++) {
            const float* px = X + (size_t)rg * K + ks * 32 + kg * 8;
            float4 x0 = *(const float4*)px;
            float4 x1 = *(const float4*)(px + 4);
            half8 vv;
            vv[0] = (_Float16)x0.x; vv[1] = (_Float16)x0.y;
            vv[2] = (_Float16)x0.z; vv[3] = (_Float16)x0.w;
            vv[4] = (_Float16)x1.x; vv[5] = (_Float16)x1.y;
            vv[6] = (_Float16)x1.z; vv[7] = (_Float16)x1.w;
            a[ks] = vv;
        }
    } else {
#pragma unroll
        for (int ks = 0; ks < 4; ks++)
            a[ks] = *(const half8*)(X + (size_t)rg * K + ks * 32 + kg * 8);
    }

    f32x4 acc[NCT];
#pragma unroll
    for (int ct = 0; ct < NCT; ct++) acc[ct] = (f32x4){0.f, 0.f, 0.f, 0.f};
#pragma unroll
    for (int ct = 0; ct < NCT; ct++) {
#pragma unroll
        for (int ks = 0; ks < 4; ks++) {
            half8 b = *(const half8*)(WT + (size_t)(ct * 16 + lr) * K + ks * 32 + kg * 8);
            acc[ct] = __builtin_amdgcn_mfma_f32_16x16x32_f16(a[ks], b, acc[ct], 0, 0, 0);
        }
    }
    // epilogue: lane's 4 values per ct are rows kg*4+i, col lr -> H[ct][row][lr]
#pragma unroll
    for (int i = 0; i < 4; i++) {
        int rr = r0 + kg * 4 + i;
        if (rr < nrows) {
            float s = SCALE ? dinv[rr] : 1.f;
            _Float16* hp = H + (size_t)rr * 16 + lr;
#pragma unroll
            for (int ct = 0; ct < NCT; ct++)
                hp[ct * cs] = (_Float16)(acc[ct][i] * s);
        }
    }
}

// ---------------- chunked aggregation: out[n] = dinv[n]*(sum h'[s] + h'[n]) + b ----------------
// HC[c][node][16] fp16, chunk slice = nn*32 B (<4 MB -> XCD-L2-resident).
// chunk = blockIdx % NCHUNK aligns chunk->XCD (dispatch round-robins XCDs).
// Wave: 4 nodes; lane = n_sub(2b) | slot(3b) | half(1b); 16 B gather per lane.
template <int NF, int NCHUNK, bool RELU, bool OUTSCALE, typename OutT>
__global__ __launch_bounds__(256) void aggc_k(const __half* __restrict__ HC,
                                              const int* __restrict__ rowptr,
                                              const int* __restrict__ csr,
                                              const float* __restrict__ dinv,
                                              const float* __restrict__ bias,
                                              OutT* __restrict__ Out, int nn) {
    constexpr int CF = 16;
    int chunk = (int)(blockIdx.x % NCHUNK);
    int ngrp = (int)(blockIdx.x / NCHUNK);
    int wv = threadIdx.x >> 6;
    int lane = threadIdx.x & 63;
    int n_sub = lane >> 4, slot = (lane >> 1) & 7, half = lane & 1;
    int nid = ngrp * 16 + wv * 4 + n_sub;
    if (nid >= nn) return;
    const __half* Hc = HC + (size_t)chunk * ((size_t)nn * CF) + half * 8;

    float acc[8];
#pragma unroll
    for (int j = 0; j < 8; j++) acc[j] = 0.f;

    int beg = rowptr[nid], end = rowptr[nid + 1];
    for (int e = beg + slot; e < end; e += 8) {
        int s = csr[e];
        HVec<4> hv = *(const HVec<4>*)(Hc + (size_t)s * CF);
#pragma unroll
        for (int q = 0; q < 4; q++) {
            float2 f = __half22float2(hv.v[q]);
            acc[2 * q + 0] += f.x;
            acc[2 * q + 1] += f.y;
        }
    }
    // reduce over the 8 slots (lane bits 1..3)
#pragma unroll
    for (int j = 0; j < 8; j++) {
        acc[j] += __shfl_xor(acc[j], 2);
        acc[j] += __shfl_xor(acc[j], 4);
        acc[j] += __shfl_xor(acc[j], 8);
    }
    if (slot == 0) {
        // self-loop (h'[nid], already scaled)
        HVec<4> hv = *(const HVec<4>*)(Hc + (size_t)nid * CF);
        float dn = dinv[nid];
        float r[8];
#pragma unroll
        for (int j = 0; j < 8; j += 2) {
            float2 f = __half22float2(hv.v[j >> 1]);
            r[j + 0] = (acc[j + 0] + f.x) * dn + bias[chunk * CF + half * 8 + j + 0];
            r[j + 1] = (acc[j + 1] + f.y) * dn + bias[chunk * CF + half * 8 + j + 1];
        }
#pragma unroll
        for (int j = 0; j < 8; j++) {
            if (RELU) r[j] = fmaxf(r[j], 0.f);
            if (OUTSCALE) r[j] *= dn;      // pre-scale for next layer's aggregation
        }
        if constexpr (std::is_same<OutT, __half>::value) {
            // row-major fp16 (read row-wise by next gemm)
            HVec<4> o;
#pragma unroll
            for (int q = 0; q < 4; q++)
                o.v[q] = __floats2half2_rn(r[2 * q], r[2 * q + 1]);
            *(HVec<4>*)(Out + (size_t)nid * NF + chunk * CF + half * 8) = o;
        } else {
            float* op = Out + (size_t)nid * NF + chunk * CF + half * 8;
            float4 o0, o1;
            o0.x = r[0]; o0.y = r[1]; o0.z = r[2]; o0.w = r[3];
            o1.x = r[4]; o1.y = r[5]; o1.z = r[6]; o1.w = r[7];
            *(float4*)op = o0;
            *(float4*)(op + 4) = o1;
        }
    }
}

// ---------------- launch ----------------

extern "C" void kernel_launch(void* const* d_in, const int* in_sizes, int n_in,
                              void* d_out, int out_size, void* d_ws, size_t ws_size,
                              hipStream_t stream) {
    const float* x  = (const float*)d_in[0];
    const int* ei   = (const int*)d_in[1];
    const float* W1 = (const float*)d_in[2];
    const float* b1 = (const float*)d_in[3];
    const float* W2 = (const float*)d_in[4];
    const float* b2 = (const float*)d_in[5];
    float* out = (float*)d_out;

    const int IN = 128, HID = 128;
    int nn = in_sizes[0] / IN;     // 100000
    int ne = in_sizes[1] / 2;      // 1600000
    const int* src = ei;
    const int* dst = ei + ne;
    int nbuckets = (nn + NPB - 1) / NPB;   // 196 (<= NBK)

    char* w = (char*)d_ws;
    size_t off = 0;
    auto take = [&](size_t bytes) -> void* {
        void* p = w + off;
        off = (off + bytes + 255) & ~(size_t)255;
        return p;
    };
    int*      gcount = (int*)take(NBK * 4);
    int*      gbase  = (int*)take((NBK + 1) * 4);
    int*      cursor = (int*)take(NBK * 4);
    int*      rowptr = (int*)take((size_t)(nn + 1) * 4);
    float*    dinv   = (float*)take((size_t)nn * 4);
    int*      csr    = (int*)take((size_t)ne * 4);
    _Float16* WT1    = (_Float16*)take(128 * 128 * 2);
    _Float16* WT2    = (_Float16*)take(64 * 128 * 2);
    __half*   hC     = (__half*)take((size_t)nn * HID * 2);   // chunked 8 x [nn][16]
    __half*   h1     = (__half*)take((size_t)nn * HID * 2);   // row-major
    __half*   h2C    = hC;                 // reuse: hC dead after agg1 (4 x [nn][16])
    int*      bucketed = (int*)hC;         // reuse: dead before gemm1 writes hC

    (void)ws_size; (void)n_in; (void)out_size;

    hipMemsetAsync(gcount, 0, NBK * 4, stream);

    int tb = 256;
    histA_k<<<(ne + 4095) / 4096, 256, 0, stream>>>(dst, ne, gcount);
    scanB_k<<<1, NBK, 0, stream>>>(gcount, gbase, cursor, rowptr, nn, ne);
    partA_k<<<(ne + 8191) / 8192, 512, 0, stream>>>(src, dst, cursor, bucketed, ne);
    csrB_k<<<nbuckets, 1024, 0, stream>>>(bucketed, gbase, csr, rowptr, dinv, nn);
    prepW_k<<<(128 * 128 + 128 * 64 + tb - 1) / tb, tb, 0, stream>>>(W1, W2, WT1, WT2);

    int gblocks = ((nn + 15) / 16 + 3) / 4;   // 1 wave per 16 rows, 4 waves/block
    int ngrp16 = (nn + 15) / 16;              // node groups of 16 for aggc

    // layer 1: hC = dinv .* (x @ W1)  [fp16, chunked] ; h1 = dinv .* relu(agg(hC) + b1)
    gemm_mfma_k<128, true, float><<<gblocks, tb, 0, stream>>>(x, WT1, dinv, (_Float16*)hC, nn);
    aggc_k<128, 8, true, true, __half><<<ngrp16 * 8, tb, 0, stream>>>(hC, rowptr, csr, dinv, b1, h1, nn);

    // layer 2: h2C = h1 @ W2 (already dinv-scaled)  [chunked] ; out = agg(h2C) + b2  [fp32]
    gemm_mfma_k<64, false, __half><<<gblocks, tb, 0, stream>>>(h1, WT2, dinv, (_Float16*)h2C, nn);
    aggc_k<64, 4, false, false, float><<<ngrp16 * 4, tb, 0, stream>>>(h2C, rowptr, csr, dinv, b2, out, nn);
}